// Round 4
// baseline (1623.384 us; speedup 1.0000x reference)
//
#include <hip/hip_runtime.h>
#include <cstdint>
#include <cstddef>

typedef unsigned short u16;
typedef short short8 __attribute__((ext_vector_type(8)));
typedef __bf16 bf16x8 __attribute__((ext_vector_type(8)));
typedef float f32x4 __attribute__((ext_vector_type(4)));

#define BB 64
#define NNODE 1024
#define EDGES 16384
#define DIM 300
#define HEADS 5
#define LAYERS 2
#define K_PAD 320
#define N_PAD 1536
#define BM 128
#define BK 32

__device__ __forceinline__ u16 f32_to_bf16(float f) {
    union { float f; uint32_t u; } v; v.f = f;
    uint32_t u = v.u;
    uint32_t r = u + 0x7fffu + ((u >> 16) & 1u);
    return (u16)(r >> 16);
}
__device__ __forceinline__ float bf16_to_f32(u16 h) {
    union { uint32_t u; float f; } v; v.u = ((uint32_t)h) << 16;
    return v.f;
}

// ---------------------------------------------------------------- CSR build
__global__ __launch_bounds__(256) void csr_build(const int* __restrict__ ei,
                                                 int* __restrict__ offs,
                                                 int* __restrict__ csr_src) {
    int b = blockIdx.x;
    const int* src = ei + (size_t)b * 2 * EDGES;
    const int* dst = src + EDGES;
    __shared__ int cnt[NNODE];
    __shared__ int grp[256];
    int t = threadIdx.x;
    for (int i = t; i < NNODE; i += 256) cnt[i] = 0;
    __syncthreads();
    for (int e = t; e < EDGES; e += 256) atomicAdd(&cnt[dst[e]], 1);
    __syncthreads();
    int c0 = cnt[4 * t + 0], c1 = cnt[4 * t + 1], c2 = cnt[4 * t + 2], c3 = cnt[4 * t + 3];
    grp[t] = c0 + c1 + c2 + c3;
    __syncthreads();
    for (int off = 1; off < 256; off <<= 1) {
        int v = (t >= off) ? grp[t - off] : 0;
        __syncthreads();
        grp[t] += v;
        __syncthreads();
    }
    int base = (t == 0) ? 0 : grp[t - 1];
    int o0 = base, o1 = o0 + c0, o2 = o1 + c1, o3 = o2 + c2;
    cnt[4 * t + 0] = o0; cnt[4 * t + 1] = o1; cnt[4 * t + 2] = o2; cnt[4 * t + 3] = o3;
    int* ob = offs + b * (NNODE + 1);
    ob[4 * t + 0] = o0; ob[4 * t + 1] = o1; ob[4 * t + 2] = o2; ob[4 * t + 3] = o3;
    if (t == 0) ob[NNODE] = EDGES;
    __syncthreads();
    for (int e = t; e < EDGES; e += 256) {
        int d = dst[e];
        int pos = atomicAdd(&cnt[d], 1);
        csr_src[(size_t)b * EDGES + pos] = src[e];
    }
}

// ------------------------------------- split W (both layers) f32 -> bf16 hi/lo, transposed
__global__ __launch_bounds__(256) void split_w_all(const float* __restrict__ W,
                                                   u16* __restrict__ hi, u16* __restrict__ lo) {
    int i = blockIdx.x * 256 + threadIdx.x;   // LAYERS*N_PAD*K_PAD exact
    int k = i % K_PAD;
    int rem = i / K_PAD;
    int n = rem % N_PAD;
    int l = rem / N_PAD;
    float v = (k < DIM && n < HEADS * DIM)
                  ? W[((size_t)l * DIM + k) * (HEADS * DIM) + n]   // transpose: Wt[n][k]
                  : 0.f;
    u16 h = f32_to_bf16(v);
    hi[i] = h;
    lo[i] = f32_to_bf16(v - bf16_to_f32(h));
}

// -------------------------------------------- pad chunk input f32 [M][300] -> [M][320]
__global__ __launch_bounds__(256) void pad_x(const float* __restrict__ X,
                                             float* __restrict__ Xp) {
    size_t i = (size_t)blockIdx.x * 256 + threadIdx.x;   // M*K_PAD exact
    int k = (int)(i % K_PAD);
    size_t row = i / K_PAD;
    Xp[i] = (k < DIM) ? X[row * DIM + k] : 0.f;
}

// ---------------------------------------------------------------- GEMM
// Hb[M, N_PAD](bf16) = Xp[M, K_PAD](f32, split in-register) * Wt[N_PAD, K_PAD]^T
__device__ __forceinline__ f32x4 mfma16(short8 a, short8 b, f32x4 c) {
    return __builtin_amdgcn_mfma_f32_16x16x32_bf16(
        __builtin_bit_cast(bf16x8, a), __builtin_bit_cast(bf16x8, b), c, 0, 0, 0);
}

__global__ __launch_bounds__(256) void gemm_split(const float* __restrict__ Xp,
                                                  const u16* __restrict__ Bhi,
                                                  const u16* __restrict__ Blo,
                                                  u16* __restrict__ Hout) {
    __shared__ __align__(16) short lds[4][BM][BK];   // Ahi, Alo, Bhi, Blo (16B-granule XOR swizzle)
    int t = threadIdx.x;
    int m0 = blockIdx.x * BM, n0 = blockIdx.y * BM;
    int lane = t & 63, w = t >> 6, wr = w >> 1, wc = w & 1;
    int lrow = lane & 15, kg = lane >> 4;

    const u16* gWh = Bhi + (size_t)n0 * K_PAD;
    const u16* gWl = Blo + (size_t)n0 * K_PAD;

    f32x4 acc[4][4] = {};

    for (int k0 = 0; k0 < K_PAD; k0 += BK) {
        __syncthreads();
        // A: load 8 f32, split to hi/lo bf16 in-register, store swizzled
#pragma unroll
        for (int i = 0; i < 2; i++) {
            int chunk = t + (i << 8);             // 0..511
            int row = chunk >> 2, g = chunk & 3;
            const float* src = &Xp[(size_t)(m0 + row) * K_PAD + k0 + g * 8];
            f32x4 v0 = *(const f32x4*)src;
            f32x4 v1 = *(const f32x4*)(src + 4);
            short8 h8, l8;
#pragma unroll
            for (int j = 0; j < 8; j++) {
                float f = (j < 4) ? v0[j] : v1[j - 4];
                u16 h = f32_to_bf16(f);
                h8[j] = (short)h;
                l8[j] = (short)f32_to_bf16(f - bf16_to_f32(h));
            }
            int gsw = (g ^ ((row >> 1) & 3)) * 8;
            *(short8*)&lds[0][row][gsw] = h8;
            *(short8*)&lds[1][row][gsw] = l8;
        }
        // B: bf16 hi/lo straight from global
#pragma unroll
        for (int i = 0; i < 4; i++) {
            int chunk = t + ((i & 1) << 8);
            int row = chunk >> 2, g = chunk & 3;
            int gsw = (g ^ ((row >> 1) & 3)) * 8;
            const u16* gs = (i < 2) ? gWh : gWl;
            short* ls = (i < 2) ? &lds[2][row][gsw] : &lds[3][row][gsw];
            *(short8*)ls = *(const short8*)&gs[(size_t)row * K_PAD + k0 + g * 8];
        }
        __syncthreads();

        short8 ah[4], al[4], bh[4], bl[4];
#pragma unroll
        for (int f = 0; f < 4; f++) {
            int ra = wr * 64 + f * 16 + lrow;
            int sa = (kg ^ ((ra >> 1) & 3)) * 8;
            ah[f] = *(const short8*)&lds[0][ra][sa];
            al[f] = *(const short8*)&lds[1][ra][sa];
            int rb = wc * 64 + f * 16 + lrow;
            int sb = (kg ^ ((rb >> 1) & 3)) * 8;
            bh[f] = *(const short8*)&lds[2][rb][sb];
            bl[f] = *(const short8*)&lds[3][rb][sb];
        }
#pragma unroll
        for (int fm = 0; fm < 4; fm++)
#pragma unroll
            for (int fn = 0; fn < 4; fn++) {
                acc[fm][fn] = mfma16(ah[fm], bh[fn], acc[fm][fn]);
                acc[fm][fn] = mfma16(ah[fm], bl[fn], acc[fm][fn]);
                acc[fm][fn] = mfma16(al[fm], bh[fn], acc[fm][fn]);
            }
    }

#pragma unroll
    for (int fm = 0; fm < 4; fm++)
#pragma unroll
        for (int fn = 0; fn < 4; fn++)
#pragma unroll
            for (int i = 0; i < 4; i++) {
                int row = m0 + wr * 64 + fm * 16 + (lane >> 4) * 4 + i;
                int col = n0 + wc * 64 + fn * 16 + (lane & 15);
                Hout[(size_t)row * N_PAD + col] = f32_to_bf16(acc[fm][fn][i]);
            }
}

// ------------------------------------------------- per-node head dots a_s,a_d
__global__ __launch_bounds__(256) void head_dots(const u16* __restrict__ Hb,
                                                 const float* __restrict__ att_s,
                                                 const float* __restrict__ att_d,
                                                 float* __restrict__ a_s,
                                                 float* __restrict__ a_d) {
    int node = blockIdx.x * 4 + (threadIdx.x >> 6);
    int lane = threadIdx.x & 63;
    const u16* row = Hb + (size_t)node * N_PAD;
#pragma unroll
    for (int hd = 0; hd < HEADS; hd++) {
        float ss = 0.f, sd = 0.f;
        for (int c = hd * DIM + lane; c < (hd + 1) * DIM; c += 64) {
            float hv = bf16_to_f32(row[c]);
            ss += hv * att_s[c];
            sd += hv * att_d[c];
        }
#pragma unroll
        for (int o = 32; o > 0; o >>= 1) {
            ss += __shfl_down(ss, o);
            sd += __shfl_down(sd, o);
        }
        if (lane == 0) {
            a_s[(size_t)node * HEADS + hd] = ss;
            a_d[(size_t)node * HEADS + hd] = sd;
        }
    }
}

// --------- fused scatter-softmax + aggregate + bias + GELU + LayerNorm
__global__ __launch_bounds__(320) void agg_kernel(const u16* __restrict__ Hb,
                                                  const float* __restrict__ a_s,
                                                  const float* __restrict__ a_d_arr,
                                                  const int* __restrict__ offs,
                                                  const int* __restrict__ csr_src,
                                                  const unsigned char* __restrict__ mask,
                                                  const float* __restrict__ bias_l,
                                                  const float* __restrict__ gamma,
                                                  const float* __restrict__ beta,
                                                  int graph0,
                                                  float* __restrict__ out,
                                                  int ldo, int do_pad) {
    // XCD-affine swizzle: consecutive blocks of one graph stay on one XCD
    int nb = blockIdx.x;
    int xcd = nb & 7;
    int j = nb >> 3;
    int b = xcd + 8 * (j >> 10);         // local graph in [0, CB)
    int n = j & 1023;
    int node = b * NNODE + n;            // chunk-local node
    int gb = graph0 + b;                 // global graph
    int t = threadIdx.x;
    int h = t % 5, et = t / 5;           // fixed head per thread (320 % 5 == 0)

    __shared__ float red[320];
    __shared__ float mh[5], dh[5];
    __shared__ float alpha[64][5];
    __shared__ int srcs[64];
    __shared__ float stat[2];

    int off0 = offs[gb * (NNODE + 1) + n];
    int off1 = offs[gb * (NNODE + 1) + n + 1];
    int deg = off1 - off0;
    const int* slist = csr_src + (size_t)gb * EDGES + off0;
    float adh = a_d_arr[(size_t)node * HEADS + h];

    // pass 1a: per-head max
    float mt = -1e30f;
    for (int e = et; e < deg; e += 64) {
        int s = slist[e];
        float sc = a_s[(size_t)(b * NNODE + s) * HEADS + h] + adh;
        sc = (sc >= 0.f) ? sc : 0.2f * sc;
        if (mask[gb * NNODE + s]) sc = -1e9f;
        mt = fmaxf(mt, sc);
    }
    red[t] = mt;
    __syncthreads();
    if (t < 5) {
        float m = -1e30f;
        for (int q = 0; q < 64; q++) m = fmaxf(m, red[t + 5 * q]);
        mh[t] = m;
    }
    __syncthreads();
    float m_h = mh[h];

    // pass 1b: per-head denominator
    float dt = 0.f;
    for (int e = et; e < deg; e += 64) {
        int s = slist[e];
        float sc = a_s[(size_t)(b * NNODE + s) * HEADS + h] + adh;
        sc = (sc >= 0.f) ? sc : 0.2f * sc;
        if (mask[gb * NNODE + s]) sc = -1e9f;
        dt += __expf(sc - m_h);
    }
    red[t] = dt;
    __syncthreads();
    if (t < 5) {
        float s = 0.f;
        for (int q = 0; q < 64; q++) s += red[t + 5 * q];
        dh[t] = s;
    }
    __syncthreads();
    float den_h = dh[h] + 1e-16f;

    // pass 2: chunked alpha + gather-accumulate
    int d = t;
    float acc0 = 0.f, acc1 = 0.f, acc2 = 0.f, acc3 = 0.f, acc4 = 0.f;
    for (int c0 = 0; c0 < deg; c0 += 64) {
        int cn = min(64, deg - c0);
        __syncthreads();
        if (t < cn * 5) {
            int e = c0 + et;
            int s = slist[e];
            float sc = a_s[(size_t)(b * NNODE + s) * HEADS + h] + adh;
            sc = (sc >= 0.f) ? sc : 0.2f * sc;
            if (mask[gb * NNODE + s]) sc = -1e9f;
            alpha[et][h] = __expf(sc - m_h) / den_h;
            if (h == 0) srcs[et] = s;
        }
        __syncthreads();
        if (d < DIM) {
            for (int e = 0; e < cn; e++) {
                const u16* hr = Hb + (size_t)(b * NNODE + srcs[e]) * N_PAD + d;
                acc0 += alpha[e][0] * bf16_to_f32(hr[0 * DIM]);
                acc1 += alpha[e][1] * bf16_to_f32(hr[1 * DIM]);
                acc2 += alpha[e][2] * bf16_to_f32(hr[2 * DIM]);
                acc3 += alpha[e][3] * bf16_to_f32(hr[3 * DIM]);
                acc4 += alpha[e][4] * bf16_to_f32(hr[4 * DIM]);
            }
        }
    }

    // epilogue: head mean + bias + GELU(tanh) then LayerNorm over DIM
    float g = 0.f;
    if (d < DIM) {
        float x = (acc0 + acc1 + acc2 + acc3 + acc4) * 0.2f + bias_l[d];
        float u = 0.7978845608028654f * (x + 0.044715f * x * x * x);
        g = 0.5f * x * (1.f + tanhf(u));
    }
    __syncthreads();
    red[t] = g;
    __syncthreads();
    for (int s = 160; s >= 5; s >>= 1) {
        if (t < s) red[t] += red[t + s];
        __syncthreads();
    }
    if (t == 0) stat[0] = (red[0] + red[1] + red[2] + red[3] + red[4]) * (1.f / DIM);
    __syncthreads();
    float mu = stat[0];
    float dv = (d < DIM) ? (g - mu) : 0.f;
    red[t] = dv * dv;
    __syncthreads();
    for (int s = 160; s >= 5; s >>= 1) {
        if (t < s) red[t] += red[t + s];
        __syncthreads();
    }
    if (t == 0) stat[1] = (red[0] + red[1] + red[2] + red[3] + red[4]) * (1.f / DIM);
    __syncthreads();
    float var = stat[1];
    if (d < DIM) {
        float y = (g - mu) * rsqrtf(var + 1e-5f) * gamma[d] + beta[d];
        out[(size_t)node * ldo + d] = y;
    } else if (do_pad) {
        out[(size_t)node * ldo + d] = 0.f;   // zero-pad k in [300,320) for next layer's GEMM
    }
}

// ---------------------------------------------------------------- launch
extern "C" void kernel_launch(void* const* d_in, const int* in_sizes, int n_in,
                              void* d_out, int out_size, void* d_ws, size_t ws_size,
                              hipStream_t stream) {
    const float* t2      = (const float*)d_in[0];
    const int*   ei      = (const int*)d_in[1];
    const unsigned char* mask = (const unsigned char*)d_in[2];
    const float* W       = (const float*)d_in[3];
    const float* att_src = (const float*)d_in[4];
    const float* att_dst = (const float*)d_in[5];
    const float* bias    = (const float*)d_in[6];
    const float* gamma   = (const float*)d_in[7];
    const float* beta    = (const float*)d_in[8];

    // ---- pick largest chunk (graphs per pass) whose workspace fits ws_size
    auto aln = [](size_t b) { return (b + 255) & ~(size_t)255; };
    auto need = [&](int CB) {
        size_t s = 0;
        s += aln((size_t)LAYERS * N_PAD * K_PAD * 2) * 2;        // W hi+lo
        s += aln((size_t)CB * NNODE * K_PAD * 4);                // Xpad
        s += aln((size_t)CB * NNODE * N_PAD * 2);                // Hb
        s += aln((size_t)CB * NNODE * HEADS * 4) * 2;            // a_s, a_d
        s += aln((size_t)BB * (NNODE + 1) * 4);                  // offs
        s += aln((size_t)BB * EDGES * 4);                        // csr
        return s;
    };
    int CB = 32;
    if (ws_size == 0) CB = 8;
    else while (CB > 8 && need(CB) > ws_size) CB >>= 1;
    const int MC = CB * NNODE;

    char* p = (char*)d_ws;
    auto alloc = [&](size_t bytes) {
        char* r = p;
        p += (bytes + 255) & ~(size_t)255;
        return r;
    };
    u16* Wthi = (u16*)alloc((size_t)LAYERS * N_PAD * K_PAD * 2);
    u16* Wtlo = (u16*)alloc((size_t)LAYERS * N_PAD * K_PAD * 2);
    float* Xpad = (float*)alloc((size_t)MC * K_PAD * 4);
    u16* Hb   = (u16*)alloc((size_t)MC * N_PAD * 2);
    float* a_s = (float*)alloc((size_t)MC * HEADS * 4);
    float* a_d = (float*)alloc((size_t)MC * HEADS * 4);
    int* offs  = (int*)alloc((size_t)BB * (NNODE + 1) * 4);
    int* csr   = (int*)alloc((size_t)BB * EDGES * 4);

    csr_build<<<BB, 256, 0, stream>>>(ei, offs, csr);
    split_w_all<<<(LAYERS * N_PAD * K_PAD) / 256, 256, 0, stream>>>(W, Wthi, Wtlo);

    for (int g0 = 0; g0 < BB; g0 += CB) {
        pad_x<<<(MC * K_PAD) / 256, 256, 0, stream>>>(t2 + (size_t)g0 * NNODE * DIM, Xpad);
        for (int l = 0; l < LAYERS; l++) {
            dim3 gg(MC / BM, N_PAD / BM);
            gemm_split<<<gg, 256, 0, stream>>>(Xpad,
                                               Wthi + (size_t)l * N_PAD * K_PAD,
                                               Wtlo + (size_t)l * N_PAD * K_PAD, Hb);
            head_dots<<<MC / 4, 256, 0, stream>>>(Hb, att_src + (size_t)l * HEADS * DIM,
                                                  att_dst + (size_t)l * HEADS * DIM, a_s, a_d);
            if (l == LAYERS - 1) {
                agg_kernel<<<MC, 320, 0, stream>>>(Hb, a_s, a_d, offs, csr, mask,
                                                   bias + (size_t)l * DIM, gamma, beta,
                                                   g0, (float*)d_out + (size_t)g0 * NNODE * DIM,
                                                   DIM, 0);
            } else {
                agg_kernel<<<MC, 320, 0, stream>>>(Hb, a_s, a_d, offs, csr, mask,
                                                   bias + (size_t)l * DIM, gamma, beta,
                                                   g0, Xpad, K_PAD, 1);
            }
        }
    }
}

// Round 5
// 1522.373 us; speedup vs baseline: 1.0664x; 1.0664x over previous
//
#include <hip/hip_runtime.h>
#include <cstdint>
#include <cstddef>

typedef unsigned short u16;
typedef short short8 __attribute__((ext_vector_type(8)));
typedef __bf16 bf16x8 __attribute__((ext_vector_type(8)));
typedef float f32x4 __attribute__((ext_vector_type(4)));

#define BB 64
#define NNODE 1024
#define EDGES 16384
#define DIM 300
#define HEADS 5
#define LAYERS 2
#define K_PAD 320
#define N_PAD 1536
#define BM 128
#define BK 32

__device__ __forceinline__ u16 f32_to_bf16(float f) {
    union { float f; uint32_t u; } v; v.f = f;
    uint32_t u = v.u;
    uint32_t r = u + 0x7fffu + ((u >> 16) & 1u);
    return (u16)(r >> 16);
}
__device__ __forceinline__ float bf16_to_f32(u16 h) {
    union { uint32_t u; float f; } v; v.u = ((uint32_t)h) << 16;
    return v.f;
}

// ---------------------------------------------------------------- CSR build
__global__ __launch_bounds__(256) void csr_build(const int* __restrict__ ei,
                                                 int* __restrict__ offs,
                                                 int* __restrict__ csr_src) {
    int b = blockIdx.x;
    const int* src = ei + (size_t)b * 2 * EDGES;
    const int* dst = src + EDGES;
    __shared__ int cnt[NNODE];
    __shared__ int grp[256];
    int t = threadIdx.x;
    for (int i = t; i < NNODE; i += 256) cnt[i] = 0;
    __syncthreads();
    for (int e = t; e < EDGES; e += 256) atomicAdd(&cnt[dst[e]], 1);
    __syncthreads();
    int c0 = cnt[4 * t + 0], c1 = cnt[4 * t + 1], c2 = cnt[4 * t + 2], c3 = cnt[4 * t + 3];
    grp[t] = c0 + c1 + c2 + c3;
    __syncthreads();
    for (int off = 1; off < 256; off <<= 1) {
        int v = (t >= off) ? grp[t - off] : 0;
        __syncthreads();
        grp[t] += v;
        __syncthreads();
    }
    int base = (t == 0) ? 0 : grp[t - 1];
    int o0 = base, o1 = o0 + c0, o2 = o1 + c1, o3 = o2 + c2;
    cnt[4 * t + 0] = o0; cnt[4 * t + 1] = o1; cnt[4 * t + 2] = o2; cnt[4 * t + 3] = o3;
    int* ob = offs + b * (NNODE + 1);
    ob[4 * t + 0] = o0; ob[4 * t + 1] = o1; ob[4 * t + 2] = o2; ob[4 * t + 3] = o3;
    if (t == 0) ob[NNODE] = EDGES;
    __syncthreads();
    for (int e = t; e < EDGES; e += 256) {
        int d = dst[e];
        int pos = atomicAdd(&cnt[d], 1);
        csr_src[(size_t)b * EDGES + pos] = src[e];
    }
}

// ------------------------------------- split W (both layers) f32 -> bf16 hi/lo, transposed
__global__ __launch_bounds__(256) void split_w_all(const float* __restrict__ W,
                                                   u16* __restrict__ hi, u16* __restrict__ lo) {
    int i = blockIdx.x * 256 + threadIdx.x;   // LAYERS*N_PAD*K_PAD exact
    int k = i % K_PAD;
    int rem = i / K_PAD;
    int n = rem % N_PAD;
    int l = rem / N_PAD;
    float v = (k < DIM && n < HEADS * DIM)
                  ? W[((size_t)l * DIM + k) * (HEADS * DIM) + n]   // transpose: Wt[n][k]
                  : 0.f;
    u16 h = f32_to_bf16(v);
    hi[i] = h;
    lo[i] = f32_to_bf16(v - bf16_to_f32(h));
}

// -------------------------------------------- pad chunk input f32 [M][300] -> [M][320]
__global__ __launch_bounds__(256) void pad_x(const float* __restrict__ X,
                                             float* __restrict__ Xp) {
    size_t i = (size_t)blockIdx.x * 256 + threadIdx.x;   // M*K_PAD exact
    int k = (int)(i % K_PAD);
    size_t row = i / K_PAD;
    Xp[i] = (k < DIM) ? X[row * DIM + k] : 0.f;
}

// ---------------------------------------------------------------- GEMM
// Hb[M, N_PAD](bf16) = Xp[M, K_PAD](f32 -> bf16-hi in-register) * (Whi+Wlo)[N_PAD, K_PAD]^T
__device__ __forceinline__ f32x4 mfma16(short8 a, short8 b, f32x4 c) {
    return __builtin_amdgcn_mfma_f32_16x16x32_bf16(
        __builtin_bit_cast(bf16x8, a), __builtin_bit_cast(bf16x8, b), c, 0, 0, 0);
}

__global__ __launch_bounds__(256) void gemm_split(const float* __restrict__ Xp,
                                                  const u16* __restrict__ Bhi,
                                                  const u16* __restrict__ Blo,
                                                  u16* __restrict__ Hout) {
    __shared__ __align__(16) short lds[3][BM][BK];   // Ahi, Bhi, Blo (16B-granule XOR swizzle)
    int t = threadIdx.x;
    int m0 = blockIdx.x * BM, n0 = blockIdx.y * BM;
    int lane = t & 63, w = t >> 6, wr = w >> 1, wc = w & 1;
    int lrow = lane & 15, kg = lane >> 4;

    const u16* gWh = Bhi + (size_t)n0 * K_PAD;
    const u16* gWl = Blo + (size_t)n0 * K_PAD;

    f32x4 acc[4][4] = {};

    for (int k0 = 0; k0 < K_PAD; k0 += BK) {
        __syncthreads();
        // A: load 8 f32, round to bf16-hi in-register, store swizzled
#pragma unroll
        for (int i = 0; i < 2; i++) {
            int chunk = t + (i << 8);             // 0..511
            int row = chunk >> 2, g = chunk & 3;
            const float* src = &Xp[(size_t)(m0 + row) * K_PAD + k0 + g * 8];
            f32x4 v0 = *(const f32x4*)src;
            f32x4 v1 = *(const f32x4*)(src + 4);
            short8 h8;
#pragma unroll
            for (int j = 0; j < 8; j++) {
                float f = (j < 4) ? v0[j] : v1[j - 4];
                h8[j] = (short)f32_to_bf16(f);
            }
            int gsw = (g ^ ((row >> 1) & 3)) * 8;
            *(short8*)&lds[0][row][gsw] = h8;
        }
        // B: bf16 hi/lo straight from global
#pragma unroll
        for (int i = 0; i < 4; i++) {
            int chunk = t + ((i & 1) << 8);
            int row = chunk >> 2, g = chunk & 3;
            int gsw = (g ^ ((row >> 1) & 3)) * 8;
            const u16* gs = (i < 2) ? gWh : gWl;
            short* ls = (i < 2) ? &lds[1][row][gsw] : &lds[2][row][gsw];
            *(short8*)ls = *(const short8*)&gs[(size_t)row * K_PAD + k0 + g * 8];
        }
        __syncthreads();

        short8 ah[4], bh[4], bl[4];
#pragma unroll
        for (int f = 0; f < 4; f++) {
            int ra = wr * 64 + f * 16 + lrow;
            int sa = (kg ^ ((ra >> 1) & 3)) * 8;
            ah[f] = *(const short8*)&lds[0][ra][sa];
            int rb = wc * 64 + f * 16 + lrow;
            int sb = (kg ^ ((rb >> 1) & 3)) * 8;
            bh[f] = *(const short8*)&lds[1][rb][sb];
            bl[f] = *(const short8*)&lds[2][rb][sb];
        }
#pragma unroll
        for (int fm = 0; fm < 4; fm++)
#pragma unroll
            for (int fn = 0; fn < 4; fn++) {
                acc[fm][fn] = mfma16(ah[fm], bl[fn], acc[fm][fn]);
                acc[fm][fn] = mfma16(ah[fm], bh[fn], acc[fm][fn]);
            }
    }

#pragma unroll
    for (int fm = 0; fm < 4; fm++)
#pragma unroll
        for (int fn = 0; fn < 4; fn++)
#pragma unroll
            for (int i = 0; i < 4; i++) {
                int row = m0 + wr * 64 + fm * 16 + (lane >> 4) * 4 + i;
                int col = n0 + wc * 64 + fn * 16 + (lane & 15);
                Hout[(size_t)row * N_PAD + col] = f32_to_bf16(acc[fm][fn][i]);
            }
}

// ------------------------------------------------- per-node head dots a_s,a_d
__global__ __launch_bounds__(256) void head_dots(const u16* __restrict__ Hb,
                                                 const float* __restrict__ att_s,
                                                 const float* __restrict__ att_d,
                                                 float* __restrict__ a_s,
                                                 float* __restrict__ a_d) {
    int node = blockIdx.x * 4 + (threadIdx.x >> 6);
    int lane = threadIdx.x & 63;
    const u16* row = Hb + (size_t)node * N_PAD;
#pragma unroll
    for (int hd = 0; hd < HEADS; hd++) {
        float ss = 0.f, sd = 0.f;
        for (int c = hd * DIM + lane; c < (hd + 1) * DIM; c += 64) {
            float hv = bf16_to_f32(row[c]);
            ss += hv * att_s[c];
            sd += hv * att_d[c];
        }
#pragma unroll
        for (int o = 32; o > 0; o >>= 1) {
            ss += __shfl_down(ss, o);
            sd += __shfl_down(sd, o);
        }
        if (lane == 0) {
            a_s[(size_t)node * HEADS + hd] = ss;
            a_d[(size_t)node * HEADS + hd] = sd;
        }
    }
}

// --------- fused scatter-softmax (online) + aggregate + bias + GELU + LayerNorm
// 320 threads = 5 waves. Score phase: wave w = head w, lane = edge slot (shuffle reduces).
// Gather phase: thread t = feature dim d. Online-softmax rescale across 64-edge chunks.
__global__ __launch_bounds__(320) void agg_kernel(const u16* __restrict__ Hb,
                                                  const float* __restrict__ a_s,
                                                  const float* __restrict__ a_d_arr,
                                                  const int* __restrict__ offs,
                                                  const int* __restrict__ csr_src,
                                                  const unsigned char* __restrict__ mask,
                                                  const float* __restrict__ bias_l,
                                                  const float* __restrict__ gamma,
                                                  const float* __restrict__ beta,
                                                  int graph0,
                                                  float* __restrict__ out,
                                                  int ldo, int do_pad) {
    // XCD-affine swizzle: consecutive blocks of one graph stay on one XCD
    int nb = blockIdx.x;
    int xcd = nb & 7;
    int j = nb >> 3;
    int b = xcd + 8 * (j >> 10);         // local graph in [0, CB)
    int n = j & 1023;
    int node = b * NNODE + n;            // chunk-local node
    int gb = graph0 + b;                 // global graph
    int t = threadIdx.x;
    int wave = t >> 6, lane = t & 63;

    __shared__ float s_p[64][HEADS];     // unnormalized exp(score - m) per chunk
    __shared__ int   s_srcs[64];
    __shared__ float s_scale[HEADS];
    __shared__ float s_den[HEADS];
    __shared__ float s_part[2][HEADS];

    int off0 = offs[gb * (NNODE + 1) + n];
    int deg = offs[gb * (NNODE + 1) + n + 1] - off0;
    const int* slist = csr_src + (size_t)gb * EDGES + off0;

    float adh = a_d_arr[(size_t)node * HEADS + wave];   // head = wave
    const float* as_g = a_s + (size_t)b * NNODE * HEADS;
    const unsigned char* mk_g = mask + (size_t)gb * NNODE;
    const u16* hbase = Hb + (size_t)b * NNODE * N_PAD + t;

    float m_run = -1e30f, den_run = 0.f;
    float acc[HEADS] = {0.f, 0.f, 0.f, 0.f, 0.f};

    for (int c0 = 0; c0 < deg; c0 += 64) {
        int cn = min(64, deg - c0);
        if (t < cn) s_srcs[t] = slist[c0 + t];
        __syncthreads();

        // ---- score phase (wave = head, lane = edge)
        float sc = -1e30f;
        if (lane < cn) {
            int s = s_srcs[lane];
            float v = as_g[s * HEADS + wave] + adh;
            v = (v >= 0.f) ? v : 0.2f * v;
            if (mk_g[s]) v = -1e9f;
            sc = v;
        }
        float cm = sc;
#pragma unroll
        for (int o = 32; o > 0; o >>= 1) cm = fmaxf(cm, __shfl_xor(cm, o));
        float m_new = fmaxf(m_run, cm);
        float scale = (m_run <= -1e29f) ? 0.f : __expf(m_run - m_new);
        float p = (lane < cn) ? __expf(sc - m_new) : 0.f;
        float ds = p;
#pragma unroll
        for (int o = 32; o > 0; o >>= 1) ds += __shfl_xor(ds, o);
        den_run = den_run * scale + ds;
        m_run = m_new;
        s_p[lane][wave] = p;
        if (lane == 0) s_scale[wave] = scale;
        __syncthreads();

        // ---- gather phase (thread = feature dim)
        if (t < DIM) {
#pragma unroll
            for (int h = 0; h < HEADS; h++) acc[h] *= s_scale[h];
            int e = 0;
            for (; e + 2 <= cn; e += 2) {
                const u16* h0 = hbase + (size_t)s_srcs[e] * N_PAD;
                const u16* h1 = hbase + (size_t)s_srcs[e + 1] * N_PAD;
                float q00 = s_p[e][0], q01 = s_p[e][1], q02 = s_p[e][2],
                      q03 = s_p[e][3], q04 = s_p[e][4];
                float q10 = s_p[e + 1][0], q11 = s_p[e + 1][1], q12 = s_p[e + 1][2],
                      q13 = s_p[e + 1][3], q14 = s_p[e + 1][4];
                acc[0] += q00 * bf16_to_f32(h0[0 * DIM]) + q10 * bf16_to_f32(h1[0 * DIM]);
                acc[1] += q01 * bf16_to_f32(h0[1 * DIM]) + q11 * bf16_to_f32(h1[1 * DIM]);
                acc[2] += q02 * bf16_to_f32(h0[2 * DIM]) + q12 * bf16_to_f32(h1[2 * DIM]);
                acc[3] += q03 * bf16_to_f32(h0[3 * DIM]) + q13 * bf16_to_f32(h1[3 * DIM]);
                acc[4] += q04 * bf16_to_f32(h0[4 * DIM]) + q14 * bf16_to_f32(h1[4 * DIM]);
            }
            if (e < cn) {
                const u16* h0 = hbase + (size_t)s_srcs[e] * N_PAD;
                acc[0] += s_p[e][0] * bf16_to_f32(h0[0 * DIM]);
                acc[1] += s_p[e][1] * bf16_to_f32(h0[1 * DIM]);
                acc[2] += s_p[e][2] * bf16_to_f32(h0[2 * DIM]);
                acc[3] += s_p[e][3] * bf16_to_f32(h0[3 * DIM]);
                acc[4] += s_p[e][4] * bf16_to_f32(h0[4 * DIM]);
            }
        }
        __syncthreads();   // protect s_p/s_srcs before next chunk
    }

    if (lane == 0) s_den[wave] = den_run + 1e-16f;
    __syncthreads();

    // epilogue: head mean + bias + GELU(tanh)
    float g = 0.f;
    if (t < DIM) {
        float x = 0.f;
#pragma unroll
        for (int h = 0; h < HEADS; h++) x += acc[h] / s_den[h];
        x = x * 0.2f + bias_l[t];
        float u = 0.7978845608028654f * (x + 0.044715f * x * x * x);
        g = 0.5f * x * (1.f + tanhf(u));
    }
    // LayerNorm via wave shuffles + 5-partial broadcast
    float sum = g;
#pragma unroll
    for (int o = 32; o > 0; o >>= 1) sum += __shfl_xor(sum, o);
    if (lane == 0) s_part[0][wave] = sum;
    __syncthreads();
    float mu = (s_part[0][0] + s_part[0][1] + s_part[0][2] + s_part[0][3] + s_part[0][4])
               * (1.f / DIM);
    float dv = (t < DIM) ? (g - mu) : 0.f;
    float sq = dv * dv;
#pragma unroll
    for (int o = 32; o > 0; o >>= 1) sq += __shfl_xor(sq, o);
    if (lane == 0) s_part[1][wave] = sq;
    __syncthreads();
    float var = (s_part[1][0] + s_part[1][1] + s_part[1][2] + s_part[1][3] + s_part[1][4])
                * (1.f / DIM);
    if (t < DIM) {
        float y = dv * rsqrtf(var + 1e-5f) * gamma[t] + beta[t];
        out[(size_t)node * ldo + t] = y;
    } else if (do_pad) {
        out[(size_t)node * ldo + t] = 0.f;   // zero-pad k in [300,320) for next layer's GEMM
    }
}

// ---------------------------------------------------------------- launch
extern "C" void kernel_launch(void* const* d_in, const int* in_sizes, int n_in,
                              void* d_out, int out_size, void* d_ws, size_t ws_size,
                              hipStream_t stream) {
    const float* t2      = (const float*)d_in[0];
    const int*   ei      = (const int*)d_in[1];
    const unsigned char* mask = (const unsigned char*)d_in[2];
    const float* W       = (const float*)d_in[3];
    const float* att_src = (const float*)d_in[4];
    const float* att_dst = (const float*)d_in[5];
    const float* bias    = (const float*)d_in[6];
    const float* gamma   = (const float*)d_in[7];
    const float* beta    = (const float*)d_in[8];

    // ---- pick largest chunk (graphs per pass) whose workspace fits ws_size
    auto aln = [](size_t b) { return (b + 255) & ~(size_t)255; };
    auto need = [&](int CB) {
        size_t s = 0;
        s += aln((size_t)LAYERS * N_PAD * K_PAD * 2) * 2;        // W hi+lo
        s += aln((size_t)CB * NNODE * K_PAD * 4);                // Xpad
        s += aln((size_t)CB * NNODE * N_PAD * 2);                // Hb
        s += aln((size_t)CB * NNODE * HEADS * 4) * 2;            // a_s, a_d
        s += aln((size_t)BB * (NNODE + 1) * 4);                  // offs
        s += aln((size_t)BB * EDGES * 4);                        // csr
        return s;
    };
    int CB = 32;
    if (ws_size == 0) CB = 8;
    else while (CB > 8 && need(CB) > ws_size) CB >>= 1;
    const int MC = CB * NNODE;

    char* p = (char*)d_ws;
    auto alloc = [&](size_t bytes) {
        char* r = p;
        p += (bytes + 255) & ~(size_t)255;
        return r;
    };
    u16* Wthi = (u16*)alloc((size_t)LAYERS * N_PAD * K_PAD * 2);
    u16* Wtlo = (u16*)alloc((size_t)LAYERS * N_PAD * K_PAD * 2);
    float* Xpad = (float*)alloc((size_t)MC * K_PAD * 4);
    u16* Hb   = (u16*)alloc((size_t)MC * N_PAD * 2);
    float* a_s = (float*)alloc((size_t)MC * HEADS * 4);
    float* a_d = (float*)alloc((size_t)MC * HEADS * 4);
    int* offs  = (int*)alloc((size_t)BB * (NNODE + 1) * 4);
    int* csr   = (int*)alloc((size_t)BB * EDGES * 4);

    csr_build<<<BB, 256, 0, stream>>>(ei, offs, csr);
    split_w_all<<<(LAYERS * N_PAD * K_PAD) / 256, 256, 0, stream>>>(W, Wthi, Wtlo);

    for (int g0 = 0; g0 < BB; g0 += CB) {
        pad_x<<<(MC * K_PAD) / 256, 256, 0, stream>>>(t2 + (size_t)g0 * NNODE * DIM, Xpad);
        for (int l = 0; l < LAYERS; l++) {
            dim3 gg(MC / BM, N_PAD / BM);
            gemm_split<<<gg, 256, 0, stream>>>(Xpad,
                                               Wthi + (size_t)l * N_PAD * K_PAD,
                                               Wtlo + (size_t)l * N_PAD * K_PAD, Hb);
            head_dots<<<MC / 4, 256, 0, stream>>>(Hb, att_src + (size_t)l * HEADS * DIM,
                                                  att_dst + (size_t)l * HEADS * DIM, a_s, a_d);
            if (l == LAYERS - 1) {
                agg_kernel<<<MC, 320, 0, stream>>>(Hb, a_s, a_d, offs, csr, mask,
                                                   bias + (size_t)l * DIM, gamma, beta,
                                                   g0, (float*)d_out + (size_t)g0 * NNODE * DIM,
                                                   DIM, 0);
            } else {
                agg_kernel<<<MC, 320, 0, stream>>>(Hb, a_s, a_d, offs, csr, mask,
                                                   bias + (size_t)l * DIM, gamma, beta,
                                                   g0, Xpad, K_PAD, 1);
            }
        }
    }
}